// Round 1
// baseline (1264.421 us; speedup 1.0000x reference)
//
#include <hip/hip_runtime.h>

constexpr int NODES = 50000;
constexpr int EDGES = 600000;
constexpr int DIM = 128;

// Stage 1: count degrees with int atomics.
__global__ __launch_bounds__(256) void deg_kernel(const int* __restrict__ src,
                                                  const int* __restrict__ dst,
                                                  int* __restrict__ deg_out,
                                                  int* __restrict__ deg_in) {
    int e = blockIdx.x * 256 + threadIdx.x;
    if (e < EDGES) {
        atomicAdd(&deg_out[src[e]], 1);
        atomicAdd(&deg_in[dst[e]], 1);
    }
}

// Stage 2: agg[dst] += feature[src] * rsqrt(max(out_deg[src],1))
// 32 lanes per edge, float4 per lane (128 dims). 8 edges per 256-thread block.
__global__ __launch_bounds__(256) void scatter_kernel(const float* __restrict__ feat,
                                                      const int* __restrict__ src,
                                                      const int* __restrict__ dst,
                                                      const int* __restrict__ deg_out,
                                                      float* __restrict__ agg) {
    int e = blockIdx.x * 8 + (threadIdx.x >> 5);
    int lane = threadIdx.x & 31;
    if (e >= EDGES) return;
    int s = src[e];
    int d = dst[e];
    int dg = deg_out[s];
    float scale = rsqrtf((float)(dg > 0 ? dg : 1));
    float4 v = reinterpret_cast<const float4*>(feat + (size_t)s * DIM)[lane];
    float* o = agg + (size_t)d * DIM + lane * 4;
    atomicAdd(o + 0, v.x * scale);
    atomicAdd(o + 1, v.y * scale);
    atomicAdd(o + 2, v.z * scale);
    atomicAdd(o + 3, v.w * scale);
}

// Stage 3: out = relu((agg * rsqrt(max(in_deg,1))) @ W + b)
// W (64KB) + 16 scaled agg rows (8KB) staged in LDS. 256 threads:
// thread = (row_half, col). Wl[k][j] reads: lanes j consecutive -> 2-way (free).
__global__ __launch_bounds__(256) void gemm_kernel(const float* __restrict__ agg,
                                                   const int* __restrict__ deg_in,
                                                   const float* __restrict__ W,
                                                   const float* __restrict__ bias,
                                                   float* __restrict__ out) {
    __shared__ float Wl[DIM * DIM];   // [k][j]
    __shared__ float Al[16][DIM];
    int tid = threadIdx.x;
    for (int i = tid; i < DIM * DIM / 4; i += 256)
        reinterpret_cast<float4*>(Wl)[i] = reinterpret_cast<const float4*>(W)[i];
    int row0 = blockIdx.x * 16;
    for (int i = tid; i < 16 * DIM / 4; i += 256) {
        int r = i >> 5;          // 32 float4 per row
        int c = i & 31;
        int node = row0 + r;
        float4 v = make_float4(0.f, 0.f, 0.f, 0.f);
        if (node < NODES) {
            v = reinterpret_cast<const float4*>(agg + (size_t)node * DIM)[c];
            int dg = deg_in[node];
            float sc = rsqrtf((float)(dg > 0 ? dg : 1));
            v.x *= sc; v.y *= sc; v.z *= sc; v.w *= sc;
        }
        reinterpret_cast<float4*>(&Al[0][0])[i] = v;
    }
    __syncthreads();
    int j = tid & 127;
    int rbase = (tid >> 7) * 8;
    float bj = bias[j];
    for (int r = rbase; r < rbase + 8; ++r) {
        float acc = 0.f;
        #pragma unroll 4
        for (int k = 0; k < DIM; ++k)
            acc = fmaf(Al[r][k], Wl[k * DIM + j], acc);
        int node = row0 + r;
        if (node < NODES)
            out[(size_t)node * DIM + j] = fmaxf(acc + bj, 0.f);
    }
}

extern "C" void kernel_launch(void* const* d_in, const int* in_sizes, int n_in,
                              void* d_out, int out_size, void* d_ws, size_t ws_size,
                              hipStream_t stream) {
    const float* feat = (const float*)d_in[0];
    const float* W    = (const float*)d_in[1];
    const float* b    = (const float*)d_in[2];
    const int*   src  = (const int*)d_in[3];
    const int*   dst  = (const int*)d_in[4];
    float* out = (float*)d_out;

    char* ws = (char*)d_ws;
    float* agg     = (float*)ws;                               // 25.6 MB
    int*   deg_out = (int*)(ws + (size_t)NODES * DIM * 4);     // 200 KB
    int*   deg_in  = deg_out + NODES;                          // 200 KB

    size_t zero_bytes = (size_t)NODES * DIM * 4 + 2 * (size_t)NODES * 4;
    hipMemsetAsync(d_ws, 0, zero_bytes, stream);

    deg_kernel<<<(EDGES + 255) / 256, 256, 0, stream>>>(src, dst, deg_out, deg_in);
    scatter_kernel<<<EDGES / 8, 256, 0, stream>>>(feat, src, dst, deg_out, agg);
    gemm_kernel<<<(NODES + 15) / 16, 256, 0, stream>>>(agg, deg_in, W, b, out);
}

// Round 2
// 296.530 us; speedup vs baseline: 4.2641x; 4.2641x over previous
//
#include <hip/hip_runtime.h>

constexpr int NODES = 50000;
constexpr int EDGES = 600000;
constexpr int DIM = 128;

// ---------------- Stage 1: degree count (int atomics, cheap) ----------------
__global__ __launch_bounds__(256) void deg_kernel(const int* __restrict__ src,
                                                  const int* __restrict__ dst,
                                                  int* __restrict__ deg_out,
                                                  int* __restrict__ deg_in) {
    int e = blockIdx.x * 256 + threadIdx.x;
    if (e < EDGES) {
        atomicAdd(&deg_out[src[e]], 1);
        atomicAdd(&deg_in[dst[e]], 1);
    }
}

// ---------------- Stage 2: exclusive scan of in-degrees (single block) ------
__global__ __launch_bounds__(1024) void scan_kernel(const int* __restrict__ deg_in,
                                                    int* __restrict__ row_start,
                                                    int* __restrict__ cursor) {
    __shared__ int wave_sums[16];
    __shared__ int carry_s;
    int tid = threadIdx.x;
    int lane = tid & 63;
    int wid = tid >> 6;
    if (tid == 0) carry_s = 0;
    __syncthreads();
    for (int base = 0; base < NODES; base += 1024) {
        int idx = base + tid;
        int v = (idx < NODES) ? deg_in[idx] : 0;
        // inclusive scan within wave
        int incl = v;
        #pragma unroll
        for (int off = 1; off < 64; off <<= 1) {
            int t = __shfl_up(incl, off, 64);
            if (lane >= off) incl += t;
        }
        if (lane == 63) wave_sums[wid] = incl;
        __syncthreads();
        if (wid == 0) {
            int wv = (lane < 16) ? wave_sums[lane] : 0;
            int wi = wv;
            #pragma unroll
            for (int off = 1; off < 16; off <<= 1) {
                int t = __shfl_up(wi, off, 64);
                if (lane >= off) wi += t;
            }
            if (lane < 16) wave_sums[lane] = wi - wv;  // exclusive
        }
        __syncthreads();
        int carry = carry_s;
        int excl = carry + wave_sums[wid] + incl - v;
        if (idx < NODES) { row_start[idx] = excl; cursor[idx] = excl; }
        __syncthreads();
        if (tid == 1023) carry_s = excl + v;   // block total + carry
        __syncthreads();
    }
}

// ---------------- Stage 3: bucket edges by dst (int atomics) ----------------
__global__ __launch_bounds__(256) void bucket_kernel(const int* __restrict__ src,
                                                     const int* __restrict__ dst,
                                                     int* __restrict__ cursor,
                                                     int* __restrict__ csr_src) {
    int e = blockIdx.x * 256 + threadIdx.x;
    if (e < EDGES) {
        int pos = atomicAdd(&cursor[dst[e]], 1);
        csr_src[pos] = src[e];
    }
}

// ---------------- Stage 4: H = (X * rsqrt(out_deg)) @ W ---------------------
// BM=64 rows/block, 256 threads. Xs 64x128 (32KB) + Ws 32x128 (16KB) in LDS.
// Thread (tr=tid>>5, j4=tid&31) computes rows tr*8..tr*8+7, cols j4*4..j4*4+3.
__global__ __launch_bounds__(256) void gemm_kernel(const float* __restrict__ X,
                                                   const int* __restrict__ deg_out,
                                                   const float* __restrict__ W,
                                                   float* __restrict__ H) {
    __shared__ float Xs[64][DIM];
    __shared__ float Ws[32][DIM];
    int tid = threadIdx.x;
    int row0 = blockIdx.x * 64;
    // stage X tile, fused rsqrt(out_deg) row scale
    for (int i = tid; i < 64 * DIM / 4; i += 256) {
        int r = i >> 5;         // 32 float4 per row
        int c4 = i & 31;
        int node = row0 + r;
        float4 v = make_float4(0.f, 0.f, 0.f, 0.f);
        if (node < NODES) {
            v = reinterpret_cast<const float4*>(X + (size_t)node * DIM)[c4];
            int dg = deg_out[node];
            float sc = rsqrtf((float)(dg > 0 ? dg : 1));
            v.x *= sc; v.y *= sc; v.z *= sc; v.w *= sc;
        }
        reinterpret_cast<float4*>(&Xs[0][0])[i] = v;
    }
    int tr = tid >> 5;
    int j4 = (tid & 31) * 4;
    float4 acc[8];
    #pragma unroll
    for (int i = 0; i < 8; ++i) acc[i] = make_float4(0.f, 0.f, 0.f, 0.f);
    for (int kk = 0; kk < 4; ++kk) {
        __syncthreads();
        // stage W chunk [kk*32 .. kk*32+31][0..127]
        for (int i = tid; i < 32 * DIM / 4; i += 256) {
            reinterpret_cast<float4*>(&Ws[0][0])[i] =
                reinterpret_cast<const float4*>(W + (size_t)kk * 32 * DIM)[i];
        }
        __syncthreads();
        #pragma unroll 8
        for (int k = 0; k < 32; ++k) {
            float4 wv = *reinterpret_cast<const float4*>(&Ws[k][j4]);
            #pragma unroll
            for (int i = 0; i < 8; ++i) {
                float x = Xs[tr * 8 + i][kk * 32 + k];
                acc[i].x = fmaf(x, wv.x, acc[i].x);
                acc[i].y = fmaf(x, wv.y, acc[i].y);
                acc[i].z = fmaf(x, wv.z, acc[i].z);
                acc[i].w = fmaf(x, wv.w, acc[i].w);
            }
        }
    }
    #pragma unroll
    for (int i = 0; i < 8; ++i) {
        int node = row0 + tr * 8 + i;
        if (node < NODES)
            *reinterpret_cast<float4*>(H + (size_t)node * DIM + j4) = acc[i];
    }
}

// ---------------- Stage 5: out[n] = relu(rsqrt(in_deg)*sum H[src] + b) ------
// One wave per node; float2 per lane (64*8B = 512B coalesced row read).
__global__ __launch_bounds__(256) void gather_kernel(const float* __restrict__ H,
                                                     const int* __restrict__ row_start,
                                                     const int* __restrict__ deg_in,
                                                     const int* __restrict__ csr_src,
                                                     const float* __restrict__ bias,
                                                     float* __restrict__ out) {
    int gw = (blockIdx.x * 256 + threadIdx.x) >> 6;   // node id
    int lane = threadIdx.x & 63;
    if (gw >= NODES) return;
    int start = row_start[gw];
    int deg = deg_in[gw];
    const float2* Hf = reinterpret_cast<const float2*>(H);
    float2 acc = make_float2(0.f, 0.f);
    for (int i0 = 0; i0 < deg; i0 += 64) {
        int nv = min(64, deg - i0);
        int sv = 0;
        if (i0 + lane < deg) sv = csr_src[start + i0 + lane];
        for (int i = 0; i < nv; ++i) {
            int s = __shfl(sv, i, 64);
            float2 h = Hf[(size_t)s * 64 + lane];
            acc.x += h.x;
            acc.y += h.y;
        }
    }
    float sc = rsqrtf((float)(deg > 0 ? deg : 1));
    float2 bb = reinterpret_cast<const float2*>(bias)[lane];
    float2 o;
    o.x = fmaxf(acc.x * sc + bb.x, 0.f);
    o.y = fmaxf(acc.y * sc + bb.y, 0.f);
    reinterpret_cast<float2*>(out)[(size_t)gw * 64 + lane] = o;
}

extern "C" void kernel_launch(void* const* d_in, const int* in_sizes, int n_in,
                              void* d_out, int out_size, void* d_ws, size_t ws_size,
                              hipStream_t stream) {
    const float* feat = (const float*)d_in[0];
    const float* W    = (const float*)d_in[1];
    const float* b    = (const float*)d_in[2];
    const int*   src  = (const int*)d_in[3];
    const int*   dst  = (const int*)d_in[4];
    float* out = (float*)d_out;

    char* ws = (char*)d_ws;
    float* H        = (float*)ws;                                 // 25.6 MB
    char*  p        = ws + (size_t)NODES * DIM * sizeof(float);
    int*   deg_out  = (int*)p;            p += (size_t)NODES * 4;
    int*   deg_in   = (int*)p;            p += (size_t)NODES * 4;
    int*   row_start= (int*)p;            p += (size_t)NODES * 4;
    int*   cursor   = (int*)p;            p += (size_t)NODES * 4;
    int*   csr_src  = (int*)p;            // 2.4 MB

    // zero only the degree counters
    hipMemsetAsync(deg_out, 0, 2 * (size_t)NODES * 4, stream);

    deg_kernel<<<(EDGES + 255) / 256, 256, 0, stream>>>(src, dst, deg_out, deg_in);
    scan_kernel<<<1, 1024, 0, stream>>>(deg_in, row_start, cursor);
    bucket_kernel<<<(EDGES + 255) / 256, 256, 0, stream>>>(src, dst, cursor, csr_src);
    gemm_kernel<<<(NODES + 63) / 64, 256, 0, stream>>>(feat, deg_out, W, H);
    gather_kernel<<<(NODES * 64 + 255) / 256, 256, 0, stream>>>(H, row_start, deg_in, csr_src, b, out);
}

// Round 3
// 245.243 us; speedup vs baseline: 5.1558x; 1.2091x over previous
//
#include <hip/hip_runtime.h>

constexpr int NODES = 50000;
constexpr int EDGES = 600000;
constexpr int DIM = 128;
constexpr int CHUNK = 1024;                       // scan chunk (256 thr x 4)
constexpr int NB_SCAN = (NODES + CHUNK - 1) / CHUNK;  // 49

__device__ __forceinline__ unsigned short f2bf(float f) {
    unsigned int b = __float_as_uint(f);
    b += 0x7fffu + ((b >> 16) & 1u);              // round-to-nearest-even
    return (unsigned short)(b >> 16);
}

// ---------------- Stage 1: degree count (int atomics) ----------------
__global__ __launch_bounds__(256) void deg_kernel(const int* __restrict__ src,
                                                  const int* __restrict__ dst,
                                                  int* __restrict__ deg_out,
                                                  int* __restrict__ deg_in) {
    int e = blockIdx.x * 256 + threadIdx.x;
    if (e < EDGES) {
        atomicAdd(&deg_out[src[e]], 1);
        atomicAdd(&deg_in[dst[e]], 1);
    }
}

// ---------------- Stage 2a: per-chunk totals ----------------
__global__ __launch_bounds__(256) void scan_partials(const int* __restrict__ deg_in,
                                                     int* __restrict__ partial) {
    __shared__ int wsum[4];
    int tid = threadIdx.x, lane = tid & 63, wid = tid >> 6;
    int base = blockIdx.x * CHUNK + tid * 4;
    int s = 0;
    #pragma unroll
    for (int i = 0; i < 4; ++i)
        if (base + i < NODES) s += deg_in[base + i];
    #pragma unroll
    for (int off = 32; off; off >>= 1) s += __shfl_down(s, off, 64);
    if (lane == 0) wsum[wid] = s;
    __syncthreads();
    if (tid == 0)
        partial[blockIdx.x] = wsum[0] + wsum[1] + wsum[2] + wsum[3];
}

// ---------------- Stage 2b: chunk-local exclusive scan + global offset ------
__global__ __launch_bounds__(256) void scan_chunks(const int* __restrict__ deg_in,
                                                   const int* __restrict__ partial,
                                                   int* __restrict__ row_start,
                                                   int* __restrict__ cursor) {
    __shared__ int wsum[4];
    __shared__ int blockoff_s;
    int b = blockIdx.x, tid = threadIdx.x, lane = tid & 63, wid = tid >> 6;
    if (wid == 0) {
        int v = (lane < b) ? partial[lane] : 0;   // NB_SCAN=49 <= 64 lanes
        #pragma unroll
        for (int off = 32; off; off >>= 1) v += __shfl_down(v, off, 64);
        if (lane == 0) blockoff_s = v;
    }
    int base = b * CHUNK + tid * 4;
    int v[4];
    int s = 0;
    #pragma unroll
    for (int i = 0; i < 4; ++i) {
        v[i] = (base + i < NODES) ? deg_in[base + i] : 0;
        s += v[i];
    }
    int incl = s;
    #pragma unroll
    for (int off = 1; off < 64; off <<= 1) {
        int t = __shfl_up(incl, off, 64);
        if (lane >= off) incl += t;
    }
    if (lane == 63) wsum[wid] = incl;
    __syncthreads();
    int wbase = 0;
    for (int w = 0; w < wid; ++w) wbase += wsum[w];
    int run = blockoff_s + wbase + incl - s;
    #pragma unroll
    for (int i = 0; i < 4; ++i) {
        if (base + i < NODES) { row_start[base + i] = run; cursor[base + i] = run; }
        run += v[i];
    }
}

// ---------------- Stage 3: bucket edges by dst ----------------
__global__ __launch_bounds__(256) void bucket_kernel(const int* __restrict__ src,
                                                     const int* __restrict__ dst,
                                                     int* __restrict__ cursor,
                                                     int* __restrict__ csr_src) {
    int e = blockIdx.x * 256 + threadIdx.x;
    if (e < EDGES) {
        int pos = atomicAdd(&cursor[dst[e]], 1);
        csr_src[pos] = src[e];
    }
}

// ---------------- Stage 4: H = (X * rsqrt(out_deg)) @ W, bf16 out ----------
__global__ __launch_bounds__(256) void gemm_kernel(const float* __restrict__ X,
                                                   const int* __restrict__ deg_out,
                                                   const float* __restrict__ W,
                                                   unsigned short* __restrict__ H) {
    __shared__ float Xs[64][DIM];
    __shared__ float Ws[32][DIM];
    int tid = threadIdx.x;
    int row0 = blockIdx.x * 64;
    for (int i = tid; i < 64 * DIM / 4; i += 256) {
        int r = i >> 5;
        int c4 = i & 31;
        int node = row0 + r;
        float4 v = make_float4(0.f, 0.f, 0.f, 0.f);
        if (node < NODES) {
            v = reinterpret_cast<const float4*>(X + (size_t)node * DIM)[c4];
            int dg = deg_out[node];
            float sc = rsqrtf((float)(dg > 0 ? dg : 1));
            v.x *= sc; v.y *= sc; v.z *= sc; v.w *= sc;
        }
        reinterpret_cast<float4*>(&Xs[0][0])[i] = v;
    }
    int tr = tid >> 5;
    int j4 = (tid & 31) * 4;
    float4 acc[8];
    #pragma unroll
    for (int i = 0; i < 8; ++i) acc[i] = make_float4(0.f, 0.f, 0.f, 0.f);
    for (int kk = 0; kk < 4; ++kk) {
        __syncthreads();
        for (int i = tid; i < 32 * DIM / 4; i += 256)
            reinterpret_cast<float4*>(&Ws[0][0])[i] =
                reinterpret_cast<const float4*>(W + (size_t)kk * 32 * DIM)[i];
        __syncthreads();
        #pragma unroll 8
        for (int k = 0; k < 32; ++k) {
            float4 wv = *reinterpret_cast<const float4*>(&Ws[k][j4]);
            #pragma unroll
            for (int i = 0; i < 8; ++i) {
                float x = Xs[tr * 8 + i][kk * 32 + k];
                acc[i].x = fmaf(x, wv.x, acc[i].x);
                acc[i].y = fmaf(x, wv.y, acc[i].y);
                acc[i].z = fmaf(x, wv.z, acc[i].z);
                acc[i].w = fmaf(x, wv.w, acc[i].w);
            }
        }
    }
    #pragma unroll
    for (int i = 0; i < 8; ++i) {
        int node = row0 + tr * 8 + i;
        if (node < NODES) {
            ushort4 h;
            h.x = f2bf(acc[i].x); h.y = f2bf(acc[i].y);
            h.z = f2bf(acc[i].z); h.w = f2bf(acc[i].w);
            *reinterpret_cast<ushort4*>(H + (size_t)node * DIM + j4) = h;
        }
    }
}

// ---------------- Stage 5: out[n] = relu(rsqrt(in_deg)*sum H[src] + b) ------
// One wave per node; one uint (2x bf16) per lane -> 256B coalesced row read.
__global__ __launch_bounds__(256) void gather_kernel(const unsigned int* __restrict__ Hu,
                                                     const int* __restrict__ row_start,
                                                     const int* __restrict__ deg_in,
                                                     const int* __restrict__ csr_src,
                                                     const float* __restrict__ bias,
                                                     float* __restrict__ out) {
    int gw = (blockIdx.x * 256 + threadIdx.x) >> 6;
    int lane = threadIdx.x & 63;
    if (gw >= NODES) return;
    int start = row_start[gw];
    int deg = deg_in[gw];
    float ax = 0.f, ay = 0.f;
    for (int i0 = 0; i0 < deg; i0 += 64) {
        int nv = min(64, deg - i0);
        int sv = 0;
        if (i0 + lane < deg) sv = csr_src[start + i0 + lane];
        for (int i = 0; i < nv; ++i) {
            int s = __shfl(sv, i, 64);
            unsigned int u = Hu[(size_t)s * 64 + lane];
            ax += __uint_as_float(u << 16);
            ay += __uint_as_float(u & 0xffff0000u);
        }
    }
    float sc = rsqrtf((float)(deg > 0 ? deg : 1));
    float2 bb = reinterpret_cast<const float2*>(bias)[lane];
    float2 o;
    o.x = fmaxf(ax * sc + bb.x, 0.f);
    o.y = fmaxf(ay * sc + bb.y, 0.f);
    reinterpret_cast<float2*>(out)[(size_t)gw * 64 + lane] = o;
}

extern "C" void kernel_launch(void* const* d_in, const int* in_sizes, int n_in,
                              void* d_out, int out_size, void* d_ws, size_t ws_size,
                              hipStream_t stream) {
    const float* feat = (const float*)d_in[0];
    const float* W    = (const float*)d_in[1];
    const float* b    = (const float*)d_in[2];
    const int*   src  = (const int*)d_in[3];
    const int*   dst  = (const int*)d_in[4];
    float* out = (float*)d_out;

    char* ws = (char*)d_ws;
    unsigned short* H = (unsigned short*)ws;                      // 12.8 MB
    char* p = ws + (size_t)NODES * DIM * sizeof(unsigned short);
    int* deg_out   = (int*)p;  p += (size_t)NODES * 4;
    int* deg_in    = (int*)p;  p += (size_t)NODES * 4;
    int* row_start = (int*)p;  p += (size_t)NODES * 4;
    int* cursor    = (int*)p;  p += (size_t)NODES * 4;
    int* partial   = (int*)p;  p += (size_t)NB_SCAN * 4;
    int* csr_src   = (int*)p;                                     // 2.4 MB

    hipMemsetAsync(deg_out, 0, 2 * (size_t)NODES * 4, stream);

    deg_kernel<<<(EDGES + 255) / 256, 256, 0, stream>>>(src, dst, deg_out, deg_in);
    scan_partials<<<NB_SCAN, 256, 0, stream>>>(deg_in, partial);
    scan_chunks<<<NB_SCAN, 256, 0, stream>>>(deg_in, partial, row_start, cursor);
    bucket_kernel<<<(EDGES + 255) / 256, 256, 0, stream>>>(src, dst, cursor, csr_src);
    gemm_kernel<<<(NODES + 63) / 64, 256, 0, stream>>>(feat, deg_out, W, H);
    gather_kernel<<<(NODES * 64 + 255) / 256, 256, 0, stream>>>(
        (const unsigned int*)H, row_start, deg_in, csr_src, b, out);
}